// Round 17
// baseline (630.468 us; speedup 1.0000x reference)
//
#include <hip/hip_runtime.h>
#include <hip/hip_bf16.h>

// ---------- types ----------
typedef __attribute__((ext_vector_type(8))) short bf16x8;   // 8 bf16 (K=32 MFMA)
typedef __attribute__((ext_vector_type(4))) short bf16x4;   // 4 bf16 (K=16 MFMA)
typedef __attribute__((ext_vector_type(4))) float f32x4;
typedef __attribute__((ext_vector_type(8))) unsigned short u16x8;
typedef unsigned short u16;

#define AS1(p) ((__attribute__((address_space(1))) void*)(p))
#define AS3(p) ((__attribute__((address_space(3))) void*)(p))
#define GLL16(g, l) __builtin_amdgcn_global_load_lds(AS1(g), AS3(l), 16, 0, 0)

__device__ __forceinline__ u16 f2bf(float x) {
  return __builtin_bit_cast(u16, __float2bfloat16(x));
}
__device__ __forceinline__ float bf2f(u16 u) {
  return __builtin_bit_cast(float, ((unsigned)u) << 16);
}
__device__ __forceinline__ f32x4 mfma16(bf16x8 a, bf16x8 b, f32x4 c) {
  return __builtin_amdgcn_mfma_f32_16x16x32_bf16(a, b, c, 0, 0, 0);
}
// K=16 MFMA (device-pass-only selection — R10 lesson)
__device__ __forceinline__ f32x4 mfma16k(bf16x4 a, bf16x4 b, f32x4 c) {
#if defined(__HIP_DEVICE_COMPILE__)
#if __has_builtin(__builtin_amdgcn_mfma_f32_16x16x16bf16_1k)
  return __builtin_amdgcn_mfma_f32_16x16x16bf16_1k(a, b, c, 0, 0, 0);
#else
  f32x4 d;
  asm volatile("v_mfma_f32_16x16x16_bf16 %0, %1, %2, %3"
               : "=v"(d)
               : "v"(a), "v"(b), "v"(c));
  return d;
#endif
#else
  (void)a; (void)b;
  return c;  // host pass: parse-only stub
#endif
}
// sum over each 16-lane row via DPP row_ror rotate-accumulate (VALU pipe)
#define DPPADD(x, ctrl)                                                            \
  ((x) + __builtin_bit_cast(float, __builtin_amdgcn_update_dpp(                    \
             0, __builtin_bit_cast(int, (x)), (ctrl), 0xf, 0xf, true)))
__device__ __forceinline__ float rsum16(float x) {
  x = DPPADD(x, 0x128);  // row_ror:8
  x = DPPADD(x, 0x124);  // row_ror:4
  x = DPPADD(x, 0x122);  // row_ror:2
  x = DPPADD(x, 0x121);  // row_ror:1
  return x;
}

// ---------- convert hs f32 -> bf16 (8 elems/thread) ----------
__global__ __launch_bounds__(256) void conv_bf16(const float* __restrict__ in,
                                                 u16* __restrict__ out) {
  size_t g = (size_t)blockIdx.x * 256 + threadIdx.x;
  const float4* p = reinterpret_cast<const float4*>(in) + g * 2;
  float4 a = p[0], b = p[1];
  u16x8 r;
  r[0] = f2bf(a.x); r[1] = f2bf(a.y); r[2] = f2bf(a.z); r[3] = f2bf(a.w);
  r[4] = f2bf(b.x); r[5] = f2bf(b.y); r[6] = f2bf(b.z); r[7] = f2bf(b.w);
  *reinterpret_cast<u16x8*>(out + g * 8) = r;
}

// ---------- transpose + convert: W[K][N] f32 -> Wt[N][K] bf16 ----------
__global__ __launch_bounds__(256) void wt_conv(const float* __restrict__ W,
                                               u16* __restrict__ Wt, int Kd, int N) {
  __shared__ float t[64][65];
  const int n0 = blockIdx.x * 64, k0 = blockIdx.y * 64;
  const int tx = threadIdx.x & 63, ty = threadIdx.x >> 6;
#pragma unroll
  for (int rr = 0; rr < 16; ++rr) {
    int r = rr * 4 + ty;
    t[r][tx] = W[(size_t)(k0 + r) * N + n0 + tx];
  }
  __syncthreads();
#pragma unroll
  for (int rr = 0; rr < 16; ++rr) {
    int r = rr * 4 + ty;
    Wt[(size_t)(n0 + r) * Kd + k0 + tx] = f2bf(t[tx][r]);
  }
}

// ---------- ilr_w strip into WcatT rows [6144,6272) ----------
__global__ __launch_bounds__(256) void ilr_strip(const float* __restrict__ ilr_w,
                                                 u16* __restrict__ WcatT) {
  int g = blockIdx.x * 256 + threadIdx.x;  // 128*2048
  int p = g >> 11, k = g & 2047;
  float v = (p < 32) ? ilr_w[k * 32 + p] : 0.f;
  WcatT[(size_t)(6144 + p) * 2048 + k] = f2bf(v);
}

// ---------- 256x256x64 8-phase GEMM (T3+T4+T2+T5 + T1 XCD swizzle) ----------
template <int MODE>
__global__ __launch_bounds__(512) void gemm8p(const u16* __restrict__ A,
                                              const u16* __restrict__ Bt, int M, int N, int Kd,
                                              u16* __restrict__ O0, u16* __restrict__ O1,
                                              u16* __restrict__ O2,
                                              float* __restrict__ coeffOut,
                                              const float* __restrict__ ilrb,
                                              float* __restrict__ Cout) {
  __shared__ __align__(16) u16 Asm[2][2][8192];
  __shared__ __align__(16) u16 Bsm[2][2][8192];
  const int tid = threadIdx.x;
  const int lane = tid & 63, wid = tid >> 6;
  const int wr = wid >> 2, wc = wid & 3;
  const int l15 = lane & 15, l4 = lane >> 4;
  const int wc1 = wc & 1, wch = wc >> 1;
  const int swzm = (l15 & 3) ^ (((l15 >> 2) & 1) << 2);
  // T1: XCD-aware bijective block swizzle (grids are %8==0: 800 and 256 blocks)
  const int nwg = gridDim.x * gridDim.y;
  int bid = blockIdx.y * gridDim.x + blockIdx.x;
  bid = (bid & 7) * (nwg >> 3) + (bid >> 3);
  const int bx = bid % gridDim.x, by = bid / gridDim.x;
  const int mT = by << 8, nT = bx << 8;
  const int nKt = Kd >> 6;

#define STG_A(kt_, h_)                                                              \
  do {                                                                              \
    if ((kt_) < nKt) {                                                              \
      _Pragma("unroll") for (int i_ = 0; i_ < 2; ++i_) {                            \
        const int s_ = tid + 512 * i_;                                              \
        const int r_ = s_ >> 3;                                                     \
        const int sc_ = (s_ & 7) ^ (r_ & 3) ^ (((r_ >> 2) & 1) << 2);               \
        GLL16(A + (size_t)(mT + (h_) * 128 + r_) * Kd + (kt_) * 64 + sc_ * 8,       \
              &Asm[(kt_) & 1][h_][0] + s_ * 8);                                     \
      }                                                                             \
    }                                                                               \
  } while (0)
#define STG_B(kt_, h_)                                                              \
  do {                                                                              \
    if ((kt_) < nKt) {                                                              \
      _Pragma("unroll") for (int i_ = 0; i_ < 2; ++i_) {                            \
        const int s_ = tid + 512 * i_;                                              \
        const int r_ = s_ >> 3;                                                     \
        const int sc_ = (s_ & 7) ^ (r_ & 3) ^ (((r_ >> 2) & 1) << 2);               \
        const int rg_ = nT + (h_) * 128 + r_;                                       \
        if (rg_ < N)                                                                \
          GLL16(Bt + (size_t)rg_ * Kd + (kt_) * 64 + sc_ * 8,                       \
                &Bsm[(kt_) & 1][h_][0] + s_ * 8);                                   \
      }                                                                             \
    }                                                                               \
  } while (0)
#define RD_A(buf_, mi_, ks_)                                                        \
  (*(const bf16x8*)((const char*)&Asm[buf_][wr][0] + 128 * ((mi_) * 16 + l15) +     \
                    16 * ((l4 + 4 * (ks_)) ^ swzm)))
#define RD_B(buf_, ni_, ks_)                                                        \
  (*(const bf16x8*)((const char*)&Bsm[buf_][wch][0] +                               \
                    128 * (wc1 * 64 + (ni_) * 16 + l15) +                           \
                    16 * ((l4 + 4 * (ks_)) ^ swzm)))
#define BARRIER __builtin_amdgcn_s_barrier()
#define LGKM0                                                                       \
  do {                                                                              \
    asm volatile("s_waitcnt lgkmcnt(0)" ::: "memory");                              \
    __builtin_amdgcn_sched_barrier(0);                                              \
  } while (0)
#define VM4 asm volatile("s_waitcnt vmcnt(4)" ::: "memory")
#define PRIO1 __builtin_amdgcn_s_setprio(1)
#define PRIO0 __builtin_amdgcn_s_setprio(0)
#define QUAD(mh_, nh_)                                                              \
  _Pragma("unroll") for (int m4_ = 0; m4_ < 4; ++m4_)                               \
  _Pragma("unroll") for (int n2_ = 0; n2_ < 2; ++n2_)                               \
  _Pragma("unroll") for (int ks_ = 0; ks_ < 2; ++ks_)                               \
      acc[(mh_) * 4 + m4_][(nh_) * 2 + n2_] =                                       \
          mfma16(Af[(mh_) * 4 + m4_][ks_], Bf[(nh_) * 2 + n2_][ks_],                \
                 acc[(mh_) * 4 + m4_][(nh_) * 2 + n2_])

  f32x4 acc[8][4];
#pragma unroll
  for (int m = 0; m < 8; ++m)
#pragma unroll
    for (int n = 0; n < 4; ++n) acc[m][n] = (f32x4){0.f, 0.f, 0.f, 0.f};
  bf16x8 Af[8][2], Bf[4][2];

  STG_A(0, 0); STG_A(0, 1); STG_B(0, 0); STG_B(0, 1); STG_A(1, 0); STG_A(1, 1);
  VM4;
  BARRIER;

#pragma unroll 1
  for (int it = 0; it < (nKt >> 1); ++it) {
    const int T = 2 * it;
#pragma unroll
    for (int mi = 0; mi < 4; ++mi)
#pragma unroll
      for (int ks = 0; ks < 2; ++ks) Af[mi][ks] = RD_A(0, mi, ks);
#pragma unroll
    for (int ni = 0; ni < 2; ++ni)
#pragma unroll
      for (int ks = 0; ks < 2; ++ks) Bf[ni][ks] = RD_B(0, ni, ks);
    STG_B(T + 1, 0);
    BARRIER; LGKM0; PRIO1; QUAD(0, 0); PRIO0;
    BARRIER;
#pragma unroll
    for (int mi = 4; mi < 8; ++mi)
#pragma unroll
      for (int ks = 0; ks < 2; ++ks) Af[mi][ks] = RD_A(0, mi, ks);
    STG_B(T + 1, 1);
    BARRIER; LGKM0; PRIO1; QUAD(1, 0); PRIO0;
    BARRIER;
#pragma unroll
    for (int ni = 2; ni < 4; ++ni)
#pragma unroll
      for (int ks = 0; ks < 2; ++ks) Bf[ni][ks] = RD_B(0, ni, ks);
    STG_A(T + 2, 0);
    BARRIER; LGKM0; PRIO1; QUAD(0, 1); PRIO0;
    BARRIER;
    STG_A(T + 2, 1);
    BARRIER; LGKM0; PRIO1; QUAD(1, 1); PRIO0;
    VM4;
    BARRIER;
#pragma unroll
    for (int mi = 0; mi < 4; ++mi)
#pragma unroll
      for (int ks = 0; ks < 2; ++ks) Af[mi][ks] = RD_A(1, mi, ks);
#pragma unroll
    for (int ni = 0; ni < 2; ++ni)
#pragma unroll
      for (int ks = 0; ks < 2; ++ks) Bf[ni][ks] = RD_B(1, ni, ks);
    STG_B(T + 2, 0);
    BARRIER; LGKM0; PRIO1; QUAD(0, 0); PRIO0;
    BARRIER;
#pragma unroll
    for (int mi = 4; mi < 8; ++mi)
#pragma unroll
      for (int ks = 0; ks < 2; ++ks) Af[mi][ks] = RD_A(1, mi, ks);
    STG_B(T + 2, 1);
    BARRIER; LGKM0; PRIO1; QUAD(1, 0); PRIO0;
    BARRIER;
#pragma unroll
    for (int ni = 2; ni < 4; ++ni)
#pragma unroll
      for (int ks = 0; ks < 2; ++ks) Bf[ni][ks] = RD_B(1, ni, ks);
    STG_A(T + 3, 0);
    BARRIER; LGKM0; PRIO1; QUAD(0, 1); PRIO0;
    BARRIER;
    STG_A(T + 3, 1);
    BARRIER; LGKM0; PRIO1; QUAD(1, 1); PRIO0;
    VM4;
    BARRIER;
  }

#pragma unroll
  for (int mi = 0; mi < 8; ++mi) {
#pragma unroll
    for (int ni = 0; ni < 4; ++ni) {
      const int col = nT + wc * 64 + ni * 16 + l15;
#pragma unroll
      for (int e = 0; e < 4; ++e) {
        const int row = mT + wr * 128 + mi * 16 + l4 * 4 + e;
        float v = acc[mi][ni][e];
        if constexpr (MODE == 1) {
          Cout[(size_t)row * N + col] = v;
        } else {
          const int bb = row >> 11, lt = row & 2047;
          if (col < 6144) {
            const int mat = col >> 11;
            u16* base = (mat == 0) ? O0 : ((mat == 1) ? O1 : O2);
            const int hh = (col >> 6) & 31, dd = col & 63;
            base[(((size_t)(bb * 32 + hh)) * 2048 + lt) * 64 + dd] = f2bf(v);
          } else {
            const int h3 = col - 6144;
            if (h3 < 32) {
              const float x = v + ilrb[h3];
              const float sig = 1.f / (1.f + expf(-x));
              const int tok = lt & 15;
              coeffOut[((size_t)(bb * 32 + h3)) * 2048 + lt] =
                  sig * (1.f / (64.f * (float)(tok + 1)));
            }
          }
        }
      }
    }
  }
  (void)M;
#undef STG_A
#undef STG_B
#undef RD_A
#undef RD_B
#undef QUAD
}

// ---------- 1-wave-per-(b,h) zero-LDS TTT scan (unroll-4 pipelined) ----------
// 128 blocks x 64 thr. unroll 4: four chunks per scheduling region — three
// future chunks' independent prep (transposes/P^T/packs/prefetch) fills the
// current chunk's serial LN->grad->update chain stalls.
__global__ __launch_bounds__(64) void ttt_scan(
    const u16* __restrict__ XC, const u16* __restrict__ XB, const u16* __restrict__ XA,
    const float* __restrict__ coeff, const float* __restrict__ lnw_g,
    const float* __restrict__ lnb_g, const float* __restrict__ W1g,
    const float* __restrict__ b1g, u16* __restrict__ XCW) {
  const int bh = blockIdx.x;
  const int b = bh >> 5, h = bh & 31;
  const int lane = threadIdx.x & 63;
  const int l15 = lane & 15, l4 = lane >> 4;

  const u16* xbb = XB + (size_t)bh * 131072;
  const u16* xcb = XC + (size_t)bh * 131072;
  const u16* xab = XA + (size_t)bh * 131072;
  const float* cob = coeff + (size_t)bh * 2048;

  float lnw4[4], lnb4[4], b1m[4];
#pragma unroll
  for (int cb = 0; cb < 4; ++cb) {
    lnw4[cb] = lnw_g[h * 64 + cb * 16 + l15];
    lnb4[cb] = lnb_g[h * 64 + cb * 16 + l15];
    b1m[cb] = b1g[h * 64 + cb * 16 + l15];
  }
  f32x4 mW[4][4];
#pragma unroll
  for (int kb = 0; kb < 4; ++kb)
#pragma unroll
    for (int cb = 0; cb < 4; ++cb)
#pragma unroll
      for (int e = 0; e < 4; ++e)
        mW[kb][cb][e] = W1g[(size_t)h * 4096 + (kb * 16 + l4 * 4 + e) * 64 + cb * 16 + l15];

  // identity B-frag: I[k=l4*4+e][n=l15] -> mfma16k(xA, I) = x in C-layout (transpose)
  bf16x4 identf;
#pragma unroll
  for (int e = 0; e < 4; ++e)
    identf[e] = (short)((l4 * 4 + e == l15) ? 0x3F80 : 0);
  const f32x4 zero4 = {0.f, 0.f, 0.f, 0.f};

  uint2 nxbA[4], nxcA[4], nxaA[4];
  float nco[4], nco15, ncoL;
  const int foA = l15 * 128 + l4 * 8;
#define PF(cc)                                                                       \
  do {                                                                               \
    const char* pb = (const char*)(xbb + (cc) * 1024);                               \
    const char* pc = (const char*)(xcb + (cc) * 1024);                               \
    const char* pa = (const char*)(xab + (cc) * 1024);                               \
    _Pragma("unroll") for (int kb = 0; kb < 4; ++kb) {                               \
      nxbA[kb] = *(const uint2*)(pb + foA + kb * 32);                                \
      nxcA[kb] = *(const uint2*)(pc + foA + kb * 32);                                \
      nxaA[kb] = *(const uint2*)(pa + foA + kb * 32);                                \
    }                                                                                \
    _Pragma("unroll") for (int e = 0; e < 4; ++e) nco[e] = cob[(cc) * 16 + l4 * 4 + e]; \
    nco15 = cob[(cc) * 16 + 15];                                                     \
    ncoL = cob[(cc) * 16 + l15];                                                     \
  } while (0)

  PF(0);

#pragma unroll 4
  for (int c = 0; c < 128; ++c) {
    bf16x4 xbA[4], xcA[4], xaA[4];
#pragma unroll
    for (int kb = 0; kb < 4; ++kb) {
      xbA[kb] = __builtin_bit_cast(bf16x4, nxbA[kb]);
      xcA[kb] = __builtin_bit_cast(bf16x4, nxcA[kb]);
      xaA[kb] = __builtin_bit_cast(bf16x4, nxaA[kb]);
    }
    float co_own[4];
#pragma unroll
    for (int e = 0; e < 4; ++e) co_own[e] = nco[e];
    const float co15 = nco15, coL = ncoL;

    // prefetch next chunk (only VMEM in steady state)
    PF((c < 127) ? (c + 1) : 127);

    // ---- C-layout operands via identity transpose (no loads) ----
    f32x4 saC[4], sbC[4], scC[4];
#pragma unroll
    for (int kb = 0; kb < 4; ++kb) {
      saC[kb] = mfma16k(xaA[kb], identf, zero4);
      sbC[kb] = mfma16k(xbA[kb], identf, zero4);
      scC[kb] = mfma16k(xcA[kb], identf, zero4);
    }

    // ---- P^T = xb @ xc^T ; pack A-frag ----
    f32x4 pT = zero4;
#pragma unroll
    for (int kb = 0; kb < 4; ++kb) pT = mfma16k(xbA[kb], xcA[kb], pT);
    bf16x4 pTf;
#pragma unroll
    for (int e = 0; e < 4; ++e) {
      const int r = l4 * 4 + e;
      pTf[e] = (short)f2bf((r <= l15) ? pT[e] * (-coL) : 0.f);
    }

    // ---- W1 master -> bf16 B-frags ----
    bf16x4 w1b[4][4];
#pragma unroll
    for (int kb = 0; kb < 4; ++kb)
#pragma unroll
      for (int cb = 0; cb < 4; ++cb)
#pragma unroll
        for (int e = 0; e < 4; ++e) w1b[kb][cb][e] = (short)f2bf(mW[kb][cb][e]);

    // ---- Z1 = xb@W1 + b1 ; o2 = xc@W1 ----
    f32x4 z[4], o2[4];
#pragma unroll
    for (int cb = 0; cb < 4; ++cb) {
      f32x4 a = {b1m[cb], b1m[cb], b1m[cb], b1m[cb]};
#pragma unroll
      for (int kb = 0; kb < 4; ++kb) a = mfma16k(xbA[kb], w1b[kb][cb], a);
      z[cb] = a;
      f32x4 a2 = zero4;
#pragma unroll
      for (int kb = 0; kb < 4; ++kb) a2 = mfma16k(xcA[kb], w1b[kb][cb], a2);
      o2[cb] = a2;
    }

    // ---- LN backward (DPP row-reductions; operands register-resident) ----
    float gr[4][4];
#pragma unroll
    for (int e = 0; e < 4; ++e) {
      float zz[4];
#pragma unroll
      for (int cb = 0; cb < 4; ++cb) zz[cb] = z[cb][e];
      float s1 = zz[0] + zz[1] + zz[2] + zz[3];
      float s2 = zz[0] * zz[0] + zz[1] * zz[1] + zz[2] * zz[2] + zz[3] * zz[3];
      s1 = rsum16(s1);
      s2 = rsum16(s2);
      const float mu = s1 * 0.015625f;
      const float var = fmaxf(s2 * 0.015625f - mu * mu, 0.f);
      const float rstd = rsqrtf(var + 1e-6f);
      float xh[4], gl[4];
#pragma unroll
      for (int cb = 0; cb < 4; ++cb) {
        xh[cb] = (zz[cb] - mu) * rstd;
        const float tgt = saC[cb][e] - sbC[cb][e];
        gl[cb] = (fmaf(lnw4[cb], xh[cb], lnb4[cb]) - tgt) * lnw4[cb];
      }
      float gs = gl[0] + gl[1] + gl[2] + gl[3];
      float gx = gl[0] * xh[0] + gl[1] * xh[1] + gl[2] * xh[2] + gl[3] * xh[3];
      gs = rsum16(gs);
      gx = rsum16(gx);
#pragma unroll
      for (int cb = 0; cb < 4; ++cb)
        gr[cb][e] = (64.f * gl[cb] - gs - xh[cb] * gx) * (rstd * 0.015625f);
    }

    // ---- column totals / prefix ----
    float gtot[4], lower[4];
#pragma unroll
    for (int cb = 0; cb < 4; ++cb) {
      const float T = gr[cb][0] + gr[cb][1] + gr[cb][2] + gr[cb][3];
      const float t1 = __shfl_xor(T, 16, 64);
      const float t2 = __shfl_xor(T, 32, 64);
      const float t3 = __shfl_xor(t1, 32, 64);
      gtot[cb] = T + t1 + t2 + t3;
      lower[cb] = ((l4 & 1) ? t1 : 0.f) + ((l4 & 2) ? (t2 + t3) : 0.f);
    }

    // ---- grad C-layout == B-frag: pack ----
    bf16x4 grB[4];
#pragma unroll
    for (int cb = 0; cb < 4; ++cb)
#pragma unroll
      for (int e = 0; e < 4; ++e) grB[cb][e] = (short)f2bf(gr[cb][e]);

    // ---- Z1_bar += (-co*P)@grad ----
#pragma unroll
    for (int cb = 0; cb < 4; ++cb) o2[cb] = mfma16k(pTf, grB[cb], o2[cb]);

    // ---- W1 update: A = -co15*xb^T (C-layout from transpose), B = grB ----
    bf16x4 xbU[4];
#pragma unroll
    for (int kb = 0; kb < 4; ++kb)
#pragma unroll
      for (int e = 0; e < 4; ++e)
        xbU[kb][e] = (short)f2bf(sbC[kb][e] * (-co15));
#pragma unroll
    for (int kb = 0; kb < 4; ++kb)
#pragma unroll
      for (int cb = 0; cb < 4; ++cb) mW[kb][cb] = mfma16k(xbU[kb], grB[cb], mW[kb][cb]);

    // ---- b1_bar, output LN, store ----
    float ov[4][4];
#pragma unroll
    for (int cb = 0; cb < 4; ++cb) {
      float pfx = lower[cb];
#pragma unroll
      for (int e = 0; e < 4; ++e) {
        pfx += gr[cb][e];
        ov[cb][e] = o2[cb][e] + fmaf(-co_own[e], pfx, b1m[cb]);
      }
    }
#pragma unroll
    for (int e = 0; e < 4; ++e) {
      float s1 = ov[0][e] + ov[1][e] + ov[2][e] + ov[3][e];
      float s2 = ov[0][e] * ov[0][e] + ov[1][e] * ov[1][e] + ov[2][e] * ov[2][e] +
                 ov[3][e] * ov[3][e];
      s1 = rsum16(s1);
      s2 = rsum16(s2);
      const float mu = s1 * 0.015625f;
      const float var = fmaxf(s2 * 0.015625f - mu * mu, 0.f);
      const float rstd = rsqrtf(var + 1e-6f);
      const size_t rowg = (size_t)(b * 2048 + c * 16 + l4 * 4 + e) * 2048 + h * 64;
#pragma unroll
      for (int cb = 0; cb < 4; ++cb) {
        const float y = scC[cb][e] + fmaf(lnw4[cb], (ov[cb][e] - mu) * rstd, lnb4[cb]);
        XCW[rowg + cb * 16 + l15] = f2bf(y);
      }
    }

#pragma unroll
    for (int cb = 0; cb < 4; ++cb) b1m[cb] = fmaf(-co15, gtot[cb], b1m[cb]);
  }
#undef PF
}

// ---------- launcher ----------
extern "C" void kernel_launch(void* const* d_in, const int* in_sizes, int n_in, void* d_out,
                              int out_size, void* d_ws, size_t ws_size, hipStream_t stream) {
  const float* hs = (const float*)d_in[0];
  const float* Wq = (const float*)d_in[1];
  const float* Wk = (const float*)d_in[2];
  const float* Wv = (const float*)d_in[3];
  const float* Wo = (const float*)d_in[4];
  const float* ilr_w = (const float*)d_in[5];
  const float* ilr_b = (const float*)d_in[6];
  const float* lnw = (const float*)d_in[7];
  const float* lnb = (const float*)d_in[8];
  const float* W1 = (const float*)d_in[9];
  const float* b1 = (const float*)d_in[10];
  float* out = (float*)d_out;

  if (ws_size < 93847552u) return;  // diagnosable clean-fail instead of device fault
  char* ws = (char*)d_ws;
  u16* hsb = (u16*)(ws + 0);                 // 33.5 MB; reused as XCW after gemm<0>
  u16* WcatT = (u16*)(ws + 33554432);        // 25.7 MB; reused as WoT after gemm<0>
  u16* XCbf = (u16*)(ws + 59244544);         // 33.5 MB
  float* coeffb = (float*)(ws + 92798976);   // 1 MB
  u16* XCW = hsb;
  u16* WoT = (u16*)(ws + 33554432);
  u16* XBbf = (u16*)d_out;                       // d_out as scratch (dead before gemm<1>)
  u16* XAbf = (u16*)((char*)d_out + 33554432);

  conv_bf16<<<8192, 256, 0, stream>>>(hs, hsb);
  wt_conv<<<dim3(32, 32), 256, 0, stream>>>(Wq, WcatT, 2048, 2048);
  wt_conv<<<dim3(32, 32), 256, 0, stream>>>(Wk, WcatT + (size_t)2048 * 2048, 2048, 2048);
  wt_conv<<<dim3(32, 32), 256, 0, stream>>>(Wv, WcatT + (size_t)4096 * 2048, 2048, 2048);
  ilr_strip<<<1024, 256, 0, stream>>>(ilr_w, WcatT);

  gemm8p<0><<<dim3(25, 32), 512, 0, stream>>>(hsb, WcatT, 8192, 6272, 2048, XCbf, XBbf, XAbf,
                                              coeffb, ilr_b, nullptr);
  wt_conv<<<dim3(32, 32), 256, 0, stream>>>(Wo, WoT, 2048, 2048);
  ttt_scan<<<128, 64, 0, stream>>>(XCbf, XBbf, XAbf, coeffb, lnw, lnb, W1, b1, XCW);
  gemm8p<1><<<dim3(8, 32), 512, 0, stream>>>(XCW, WoT, 8192, 2048, 2048, nullptr, nullptr,
                                             nullptr, nullptr, nullptr, out);

  (void)in_sizes; (void)n_in; (void)out_size;
}

// Round 18
// 624.758 us; speedup vs baseline: 1.0091x; 1.0091x over previous
//
#include <hip/hip_runtime.h>
#include <hip/hip_bf16.h>

// ---------- types ----------
typedef __attribute__((ext_vector_type(8))) short bf16x8;   // 8 bf16 (K=32 MFMA)
typedef __attribute__((ext_vector_type(4))) short bf16x4;   // 4 bf16 (K=16 MFMA)
typedef __attribute__((ext_vector_type(4))) float f32x4;
typedef __attribute__((ext_vector_type(8))) unsigned short u16x8;
typedef unsigned short u16;

#define AS1(p) ((__attribute__((address_space(1))) void*)(p))
#define AS3(p) ((__attribute__((address_space(3))) void*)(p))
#define GLL16(g, l) __builtin_amdgcn_global_load_lds(AS1(g), AS3(l), 16, 0, 0)

__device__ __forceinline__ u16 f2bf(float x) {
  return __builtin_bit_cast(u16, __float2bfloat16(x));
}
__device__ __forceinline__ float bf2f(u16 u) {
  return __builtin_bit_cast(float, ((unsigned)u) << 16);
}
__device__ __forceinline__ f32x4 mfma16(bf16x8 a, bf16x8 b, f32x4 c) {
  return __builtin_amdgcn_mfma_f32_16x16x32_bf16(a, b, c, 0, 0, 0);
}
// K=16 MFMA (device-pass-only selection — R10 lesson)
__device__ __forceinline__ f32x4 mfma16k(bf16x4 a, bf16x4 b, f32x4 c) {
#if defined(__HIP_DEVICE_COMPILE__)
#if __has_builtin(__builtin_amdgcn_mfma_f32_16x16x16bf16_1k)
  return __builtin_amdgcn_mfma_f32_16x16x16bf16_1k(a, b, c, 0, 0, 0);
#else
  f32x4 d;
  asm volatile("v_mfma_f32_16x16x16_bf16 %0, %1, %2, %3"
               : "=v"(d)
               : "v"(a), "v"(b), "v"(c));
  return d;
#endif
#else
  (void)a; (void)b;
  return c;  // host pass: parse-only stub
#endif
}
// sum over each 16-lane row via DPP row_ror rotate-accumulate (VALU pipe)
#define DPPADD(x, ctrl)                                                            \
  ((x) + __builtin_bit_cast(float, __builtin_amdgcn_update_dpp(                    \
             0, __builtin_bit_cast(int, (x)), (ctrl), 0xf, 0xf, true)))
__device__ __forceinline__ float rsum16(float x) {
  x = DPPADD(x, 0x128);  // row_ror:8
  x = DPPADD(x, 0x124);  // row_ror:4
  x = DPPADD(x, 0x122);  // row_ror:2
  x = DPPADD(x, 0x121);  // row_ror:1
  return x;
}

// ---------- convert hs f32 -> bf16 (8 elems/thread) ----------
__global__ __launch_bounds__(256) void conv_bf16(const float* __restrict__ in,
                                                 u16* __restrict__ out) {
  size_t g = (size_t)blockIdx.x * 256 + threadIdx.x;
  const float4* p = reinterpret_cast<const float4*>(in) + g * 2;
  float4 a = p[0], b = p[1];
  u16x8 r;
  r[0] = f2bf(a.x); r[1] = f2bf(a.y); r[2] = f2bf(a.z); r[3] = f2bf(a.w);
  r[4] = f2bf(b.x); r[5] = f2bf(b.y); r[6] = f2bf(b.z); r[7] = f2bf(b.w);
  *reinterpret_cast<u16x8*>(out + g * 8) = r;
}

// ---------- transpose + convert: W[K][N] f32 -> Wt[N][K] bf16 ----------
__global__ __launch_bounds__(256) void wt_conv(const float* __restrict__ W,
                                               u16* __restrict__ Wt, int Kd, int N) {
  __shared__ float t[64][65];
  const int n0 = blockIdx.x * 64, k0 = blockIdx.y * 64;
  const int tx = threadIdx.x & 63, ty = threadIdx.x >> 6;
#pragma unroll
  for (int rr = 0; rr < 16; ++rr) {
    int r = rr * 4 + ty;
    t[r][tx] = W[(size_t)(k0 + r) * N + n0 + tx];
  }
  __syncthreads();
#pragma unroll
  for (int rr = 0; rr < 16; ++rr) {
    int r = rr * 4 + ty;
    Wt[(size_t)(n0 + r) * Kd + k0 + tx] = f2bf(t[tx][r]);
  }
}

// ---------- ilr_w strip into WcatT rows [6144,6272) ----------
__global__ __launch_bounds__(256) void ilr_strip(const float* __restrict__ ilr_w,
                                                 u16* __restrict__ WcatT) {
  int g = blockIdx.x * 256 + threadIdx.x;  // 128*2048
  int p = g >> 11, k = g & 2047;
  float v = (p < 32) ? ilr_w[k * 32 + p] : 0.f;
  WcatT[(size_t)(6144 + p) * 2048 + k] = f2bf(v);
}

// ---------- 256x256x64 8-phase GEMM (T3+T4+T2+T5 + T1 XCD swizzle) ----------
template <int MODE>
__global__ __launch_bounds__(512) void gemm8p(const u16* __restrict__ A,
                                              const u16* __restrict__ Bt, int M, int N, int Kd,
                                              u16* __restrict__ O0, u16* __restrict__ O1,
                                              u16* __restrict__ O2,
                                              float* __restrict__ coeffOut,
                                              const float* __restrict__ ilrb,
                                              float* __restrict__ Cout) {
  __shared__ __align__(16) u16 Asm[2][2][8192];
  __shared__ __align__(16) u16 Bsm[2][2][8192];
  const int tid = threadIdx.x;
  const int lane = tid & 63, wid = tid >> 6;
  const int wr = wid >> 2, wc = wid & 3;
  const int l15 = lane & 15, l4 = lane >> 4;
  const int wc1 = wc & 1, wch = wc >> 1;
  const int swzm = (l15 & 3) ^ (((l15 >> 2) & 1) << 2);
  // T1: XCD-aware bijective block swizzle (grids are %8==0: 800 and 256 blocks)
  const int nwg = gridDim.x * gridDim.y;
  int bid = blockIdx.y * gridDim.x + blockIdx.x;
  bid = (bid & 7) * (nwg >> 3) + (bid >> 3);
  const int bx = bid % gridDim.x, by = bid / gridDim.x;
  const int mT = by << 8, nT = bx << 8;
  const int nKt = Kd >> 6;

#define STG_A(kt_, h_)                                                              \
  do {                                                                              \
    if ((kt_) < nKt) {                                                              \
      _Pragma("unroll") for (int i_ = 0; i_ < 2; ++i_) {                            \
        const int s_ = tid + 512 * i_;                                              \
        const int r_ = s_ >> 3;                                                     \
        const int sc_ = (s_ & 7) ^ (r_ & 3) ^ (((r_ >> 2) & 1) << 2);               \
        GLL16(A + (size_t)(mT + (h_) * 128 + r_) * Kd + (kt_) * 64 + sc_ * 8,       \
              &Asm[(kt_) & 1][h_][0] + s_ * 8);                                     \
      }                                                                             \
    }                                                                               \
  } while (0)
#define STG_B(kt_, h_)                                                              \
  do {                                                                              \
    if ((kt_) < nKt) {                                                              \
      _Pragma("unroll") for (int i_ = 0; i_ < 2; ++i_) {                            \
        const int s_ = tid + 512 * i_;                                              \
        const int r_ = s_ >> 3;                                                     \
        const int sc_ = (s_ & 7) ^ (r_ & 3) ^ (((r_ >> 2) & 1) << 2);               \
        const int rg_ = nT + (h_) * 128 + r_;                                       \
        if (rg_ < N)                                                                \
          GLL16(Bt + (size_t)rg_ * Kd + (kt_) * 64 + sc_ * 8,                       \
                &Bsm[(kt_) & 1][h_][0] + s_ * 8);                                   \
      }                                                                             \
    }                                                                               \
  } while (0)
#define RD_A(buf_, mi_, ks_)                                                        \
  (*(const bf16x8*)((const char*)&Asm[buf_][wr][0] + 128 * ((mi_) * 16 + l15) +     \
                    16 * ((l4 + 4 * (ks_)) ^ swzm)))
#define RD_B(buf_, ni_, ks_)                                                        \
  (*(const bf16x8*)((const char*)&Bsm[buf_][wch][0] +                               \
                    128 * (wc1 * 64 + (ni_) * 16 + l15) +                           \
                    16 * ((l4 + 4 * (ks_)) ^ swzm)))
#define BARRIER __builtin_amdgcn_s_barrier()
#define LGKM0                                                                       \
  do {                                                                              \
    asm volatile("s_waitcnt lgkmcnt(0)" ::: "memory");                              \
    __builtin_amdgcn_sched_barrier(0);                                              \
  } while (0)
#define VM4 asm volatile("s_waitcnt vmcnt(4)" ::: "memory")
#define PRIO1 __builtin_amdgcn_s_setprio(1)
#define PRIO0 __builtin_amdgcn_s_setprio(0)
#define QUAD(mh_, nh_)                                                              \
  _Pragma("unroll") for (int m4_ = 0; m4_ < 4; ++m4_)                               \
  _Pragma("unroll") for (int n2_ = 0; n2_ < 2; ++n2_)                               \
  _Pragma("unroll") for (int ks_ = 0; ks_ < 2; ++ks_)                               \
      acc[(mh_) * 4 + m4_][(nh_) * 2 + n2_] =                                       \
          mfma16(Af[(mh_) * 4 + m4_][ks_], Bf[(nh_) * 2 + n2_][ks_],                \
                 acc[(mh_) * 4 + m4_][(nh_) * 2 + n2_])

  f32x4 acc[8][4];
#pragma unroll
  for (int m = 0; m < 8; ++m)
#pragma unroll
    for (int n = 0; n < 4; ++n) acc[m][n] = (f32x4){0.f, 0.f, 0.f, 0.f};
  bf16x8 Af[8][2], Bf[4][2];

  STG_A(0, 0); STG_A(0, 1); STG_B(0, 0); STG_B(0, 1); STG_A(1, 0); STG_A(1, 1);
  VM4;
  BARRIER;

#pragma unroll 1
  for (int it = 0; it < (nKt >> 1); ++it) {
    const int T = 2 * it;
#pragma unroll
    for (int mi = 0; mi < 4; ++mi)
#pragma unroll
      for (int ks = 0; ks < 2; ++ks) Af[mi][ks] = RD_A(0, mi, ks);
#pragma unroll
    for (int ni = 0; ni < 2; ++ni)
#pragma unroll
      for (int ks = 0; ks < 2; ++ks) Bf[ni][ks] = RD_B(0, ni, ks);
    STG_B(T + 1, 0);
    BARRIER; LGKM0; PRIO1; QUAD(0, 0); PRIO0;
    BARRIER;
#pragma unroll
    for (int mi = 4; mi < 8; ++mi)
#pragma unroll
      for (int ks = 0; ks < 2; ++ks) Af[mi][ks] = RD_A(0, mi, ks);
    STG_B(T + 1, 1);
    BARRIER; LGKM0; PRIO1; QUAD(1, 0); PRIO0;
    BARRIER;
#pragma unroll
    for (int ni = 2; ni < 4; ++ni)
#pragma unroll
      for (int ks = 0; ks < 2; ++ks) Bf[ni][ks] = RD_B(0, ni, ks);
    STG_A(T + 2, 0);
    BARRIER; LGKM0; PRIO1; QUAD(0, 1); PRIO0;
    BARRIER;
    STG_A(T + 2, 1);
    BARRIER; LGKM0; PRIO1; QUAD(1, 1); PRIO0;
    VM4;
    BARRIER;
#pragma unroll
    for (int mi = 0; mi < 4; ++mi)
#pragma unroll
      for (int ks = 0; ks < 2; ++ks) Af[mi][ks] = RD_A(1, mi, ks);
#pragma unroll
    for (int ni = 0; ni < 2; ++ni)
#pragma unroll
      for (int ks = 0; ks < 2; ++ks) Bf[ni][ks] = RD_B(1, ni, ks);
    STG_B(T + 2, 0);
    BARRIER; LGKM0; PRIO1; QUAD(0, 0); PRIO0;
    BARRIER;
#pragma unroll
    for (int mi = 4; mi < 8; ++mi)
#pragma unroll
      for (int ks = 0; ks < 2; ++ks) Af[mi][ks] = RD_A(1, mi, ks);
    STG_B(T + 2, 1);
    BARRIER; LGKM0; PRIO1; QUAD(1, 0); PRIO0;
    BARRIER;
#pragma unroll
    for (int ni = 2; ni < 4; ++ni)
#pragma unroll
      for (int ks = 0; ks < 2; ++ks) Bf[ni][ks] = RD_B(1, ni, ks);
    STG_A(T + 3, 0);
    BARRIER; LGKM0; PRIO1; QUAD(0, 1); PRIO0;
    BARRIER;
    STG_A(T + 3, 1);
    BARRIER; LGKM0; PRIO1; QUAD(1, 1); PRIO0;
    VM4;
    BARRIER;
  }

#pragma unroll
  for (int mi = 0; mi < 8; ++mi) {
#pragma unroll
    for (int ni = 0; ni < 4; ++ni) {
      const int col = nT + wc * 64 + ni * 16 + l15;
#pragma unroll
      for (int e = 0; e < 4; ++e) {
        const int row = mT + wr * 128 + mi * 16 + l4 * 4 + e;
        float v = acc[mi][ni][e];
        if constexpr (MODE == 1) {
          Cout[(size_t)row * N + col] = v;
        } else {
          const int bb = row >> 11, lt = row & 2047;
          if (col < 6144) {
            const int mat = col >> 11;
            u16* base = (mat == 0) ? O0 : ((mat == 1) ? O1 : O2);
            const int hh = (col >> 6) & 31, dd = col & 63;
            base[(((size_t)(bb * 32 + hh)) * 2048 + lt) * 64 + dd] = f2bf(v);
          } else {
            const int h3 = col - 6144;
            if (h3 < 32) {
              const float x = v + ilrb[h3];
              const float sig = 1.f / (1.f + expf(-x));
              const int tok = lt & 15;
              coeffOut[((size_t)(bb * 32 + h3)) * 2048 + lt] =
                  sig * (1.f / (64.f * (float)(tok + 1)));
            }
          }
        }
      }
    }
  }
  (void)M;
#undef STG_A
#undef STG_B
#undef RD_A
#undef RD_B
#undef QUAD
}

// ---------- 1-wave-per-(b,h) zero-LDS TTT scan (unroll-2 pipelined, R16-proven) ----------
// 128 blocks x 64 thr. unroll 2 is the measured optimum (R16: 245us; R17 unroll-4
// regressed to 287us via register pressure, VGPR 168->220).
__global__ __launch_bounds__(64) void ttt_scan(
    const u16* __restrict__ XC, const u16* __restrict__ XB, const u16* __restrict__ XA,
    const float* __restrict__ coeff, const float* __restrict__ lnw_g,
    const float* __restrict__ lnb_g, const float* __restrict__ W1g,
    const float* __restrict__ b1g, u16* __restrict__ XCW) {
  const int bh = blockIdx.x;
  const int b = bh >> 5, h = bh & 31;
  const int lane = threadIdx.x & 63;
  const int l15 = lane & 15, l4 = lane >> 4;

  const u16* xbb = XB + (size_t)bh * 131072;
  const u16* xcb = XC + (size_t)bh * 131072;
  const u16* xab = XA + (size_t)bh * 131072;
  const float* cob = coeff + (size_t)bh * 2048;

  float lnw4[4], lnb4[4], b1m[4];
#pragma unroll
  for (int cb = 0; cb < 4; ++cb) {
    lnw4[cb] = lnw_g[h * 64 + cb * 16 + l15];
    lnb4[cb] = lnb_g[h * 64 + cb * 16 + l15];
    b1m[cb] = b1g[h * 64 + cb * 16 + l15];
  }
  f32x4 mW[4][4];
#pragma unroll
  for (int kb = 0; kb < 4; ++kb)
#pragma unroll
    for (int cb = 0; cb < 4; ++cb)
#pragma unroll
      for (int e = 0; e < 4; ++e)
        mW[kb][cb][e] = W1g[(size_t)h * 4096 + (kb * 16 + l4 * 4 + e) * 64 + cb * 16 + l15];

  // identity B-frag: I[k=l4*4+e][n=l15] -> mfma16k(xA, I) = x in C-layout (transpose)
  bf16x4 identf;
#pragma unroll
  for (int e = 0; e < 4; ++e)
    identf[e] = (short)((l4 * 4 + e == l15) ? 0x3F80 : 0);
  const f32x4 zero4 = {0.f, 0.f, 0.f, 0.f};

  uint2 nxbA[4], nxcA[4], nxaA[4];
  float nco[4], nco15, ncoL;
  const int foA = l15 * 128 + l4 * 8;
#define PF(cc)                                                                       \
  do {                                                                               \
    const char* pb = (const char*)(xbb + (cc) * 1024);                               \
    const char* pc = (const char*)(xcb + (cc) * 1024);                               \
    const char* pa = (const char*)(xab + (cc) * 1024);                               \
    _Pragma("unroll") for (int kb = 0; kb < 4; ++kb) {                               \
      nxbA[kb] = *(const uint2*)(pb + foA + kb * 32);                                \
      nxcA[kb] = *(const uint2*)(pc + foA + kb * 32);                                \
      nxaA[kb] = *(const uint2*)(pa + foA + kb * 32);                                \
    }                                                                                \
    _Pragma("unroll") for (int e = 0; e < 4; ++e) nco[e] = cob[(cc) * 16 + l4 * 4 + e]; \
    nco15 = cob[(cc) * 16 + 15];                                                     \
    ncoL = cob[(cc) * 16 + l15];                                                     \
  } while (0)

  PF(0);

#pragma unroll 2
  for (int c = 0; c < 128; ++c) {
    bf16x4 xbA[4], xcA[4], xaA[4];
#pragma unroll
    for (int kb = 0; kb < 4; ++kb) {
      xbA[kb] = __builtin_bit_cast(bf16x4, nxbA[kb]);
      xcA[kb] = __builtin_bit_cast(bf16x4, nxcA[kb]);
      xaA[kb] = __builtin_bit_cast(bf16x4, nxaA[kb]);
    }
    float co_own[4];
#pragma unroll
    for (int e = 0; e < 4; ++e) co_own[e] = nco[e];
    const float co15 = nco15, coL = ncoL;

    // prefetch next chunk (only VMEM in steady state)
    PF((c < 127) ? (c + 1) : 127);

    // ---- C-layout operands via identity transpose (no loads) ----
    f32x4 saC[4], sbC[4], scC[4];
#pragma unroll
    for (int kb = 0; kb < 4; ++kb) {
      saC[kb] = mfma16k(xaA[kb], identf, zero4);
      sbC[kb] = mfma16k(xbA[kb], identf, zero4);
      scC[kb] = mfma16k(xcA[kb], identf, zero4);
    }

    // ---- P^T = xb @ xc^T ; pack A-frag ----
    f32x4 pT = zero4;
#pragma unroll
    for (int kb = 0; kb < 4; ++kb) pT = mfma16k(xbA[kb], xcA[kb], pT);
    bf16x4 pTf;
#pragma unroll
    for (int e = 0; e < 4; ++e) {
      const int r = l4 * 4 + e;
      pTf[e] = (short)f2bf((r <= l15) ? pT[e] * (-coL) : 0.f);
    }

    // ---- W1 master -> bf16 B-frags ----
    bf16x4 w1b[4][4];
#pragma unroll
    for (int kb = 0; kb < 4; ++kb)
#pragma unroll
      for (int cb = 0; cb < 4; ++cb)
#pragma unroll
        for (int e = 0; e < 4; ++e) w1b[kb][cb][e] = (short)f2bf(mW[kb][cb][e]);

    // ---- Z1 = xb@W1 + b1 ; o2 = xc@W1 ----
    f32x4 z[4], o2[4];
#pragma unroll
    for (int cb = 0; cb < 4; ++cb) {
      f32x4 a = {b1m[cb], b1m[cb], b1m[cb], b1m[cb]};
#pragma unroll
      for (int kb = 0; kb < 4; ++kb) a = mfma16k(xbA[kb], w1b[kb][cb], a);
      z[cb] = a;
      f32x4 a2 = zero4;
#pragma unroll
      for (int kb = 0; kb < 4; ++kb) a2 = mfma16k(xcA[kb], w1b[kb][cb], a2);
      o2[cb] = a2;
    }

    // ---- LN backward (DPP row-reductions; operands register-resident) ----
    float gr[4][4];
#pragma unroll
    for (int e = 0; e < 4; ++e) {
      float zz[4];
#pragma unroll
      for (int cb = 0; cb < 4; ++cb) zz[cb] = z[cb][e];
      float s1 = zz[0] + zz[1] + zz[2] + zz[3];
      float s2 = zz[0] * zz[0] + zz[1] * zz[1] + zz[2] * zz[2] + zz[3] * zz[3];
      s1 = rsum16(s1);
      s2 = rsum16(s2);
      const float mu = s1 * 0.015625f;
      const float var = fmaxf(s2 * 0.015625f - mu * mu, 0.f);
      const float rstd = rsqrtf(var + 1e-6f);
      float xh[4], gl[4];
#pragma unroll
      for (int cb = 0; cb < 4; ++cb) {
        xh[cb] = (zz[cb] - mu) * rstd;
        const float tgt = saC[cb][e] - sbC[cb][e];
        gl[cb] = (fmaf(lnw4[cb], xh[cb], lnb4[cb]) - tgt) * lnw4[cb];
      }
      float gs = gl[0] + gl[1] + gl[2] + gl[3];
      float gx = gl[0] * xh[0] + gl[1] * xh[1] + gl[2] * xh[2] + gl[3] * xh[3];
      gs = rsum16(gs);
      gx = rsum16(gx);
#pragma unroll
      for (int cb = 0; cb < 4; ++cb)
        gr[cb][e] = (64.f * gl[cb] - gs - xh[cb] * gx) * (rstd * 0.015625f);
    }

    // ---- column totals / prefix ----
    float gtot[4], lower[4];
#pragma unroll
    for (int cb = 0; cb < 4; ++cb) {
      const float T = gr[cb][0] + gr[cb][1] + gr[cb][2] + gr[cb][3];
      const float t1 = __shfl_xor(T, 16, 64);
      const float t2 = __shfl_xor(T, 32, 64);
      const float t3 = __shfl_xor(t1, 32, 64);
      gtot[cb] = T + t1 + t2 + t3;
      lower[cb] = ((l4 & 1) ? t1 : 0.f) + ((l4 & 2) ? (t2 + t3) : 0.f);
    }

    // ---- grad C-layout == B-frag: pack ----
    bf16x4 grB[4];
#pragma unroll
    for (int cb = 0; cb < 4; ++cb)
#pragma unroll
      for (int e = 0; e < 4; ++e) grB[cb][e] = (short)f2bf(gr[cb][e]);

    // ---- Z1_bar += (-co*P)@grad ----
#pragma unroll
    for (int cb = 0; cb < 4; ++cb) o2[cb] = mfma16k(pTf, grB[cb], o2[cb]);

    // ---- W1 update: A = -co15*xb^T (C-layout from transpose), B = grB ----
    bf16x4 xbU[4];
#pragma unroll
    for (int kb = 0; kb < 4; ++kb)
#pragma unroll
      for (int e = 0; e < 4; ++e)
        xbU[kb][e] = (short)f2bf(sbC[kb][e] * (-co15));
#pragma unroll
    for (int kb = 0; kb < 4; ++kb)
#pragma unroll
      for (int cb = 0; cb < 4; ++cb) mW[kb][cb] = mfma16k(xbU[kb], grB[cb], mW[kb][cb]);

    // ---- b1_bar, output LN, store ----
    float ov[4][4];
#pragma unroll
    for (int cb = 0; cb < 4; ++cb) {
      float pfx = lower[cb];
#pragma unroll
      for (int e = 0; e < 4; ++e) {
        pfx += gr[cb][e];
        ov[cb][e] = o2[cb][e] + fmaf(-co_own[e], pfx, b1m[cb]);
      }
    }
#pragma unroll
    for (int e = 0; e < 4; ++e) {
      float s1 = ov[0][e] + ov[1][e] + ov[2][e] + ov[3][e];
      float s2 = ov[0][e] * ov[0][e] + ov[1][e] * ov[1][e] + ov[2][e] * ov[2][e] +
                 ov[3][e] * ov[3][e];
      s1 = rsum16(s1);
      s2 = rsum16(s2);
      const float mu = s1 * 0.015625f;
      const float var = fmaxf(s2 * 0.015625f - mu * mu, 0.f);
      const float rstd = rsqrtf(var + 1e-6f);
      const size_t rowg = (size_t)(b * 2048 + c * 16 + l4 * 4 + e) * 2048 + h * 64;
#pragma unroll
      for (int cb = 0; cb < 4; ++cb) {
        const float y = scC[cb][e] + fmaf(lnw4[cb], (ov[cb][e] - mu) * rstd, lnb4[cb]);
        XCW[rowg + cb * 16 + l15] = f2bf(y);
      }
    }

#pragma unroll
    for (int cb = 0; cb < 4; ++cb) b1m[cb] = fmaf(-co15, gtot[cb], b1m[cb]);
  }
#undef PF
}

// ---------- launcher ----------
extern "C" void kernel_launch(void* const* d_in, const int* in_sizes, int n_in, void* d_out,
                              int out_size, void* d_ws, size_t ws_size, hipStream_t stream) {
  const float* hs = (const float*)d_in[0];
  const float* Wq = (const float*)d_in[1];
  const float* Wk = (const float*)d_in[2];
  const float* Wv = (const float*)d_in[3];
  const float* Wo = (const float*)d_in[4];
  const float* ilr_w = (const float*)d_in[5];
  const float* ilr_b = (const float*)d_in[6];
  const float* lnw = (const float*)d_in[7];
  const float* lnb = (const float*)d_in[8];
  const float* W1 = (const float*)d_in[9];
  const float* b1 = (const float*)d_in[10];
  float* out = (float*)d_out;

  if (ws_size < 93847552u) return;  // diagnosable clean-fail instead of device fault
  char* ws = (char*)d_ws;
  u16* hsb = (u16*)(ws + 0);                 // 33.5 MB; reused as XCW after gemm<0>
  u16* WcatT = (u16*)(ws + 33554432);        // 25.7 MB; reused as WoT after gemm<0>
  u16* XCbf = (u16*)(ws + 59244544);         // 33.5 MB
  float* coeffb = (float*)(ws + 92798976);   // 1 MB
  u16* XCW = hsb;
  u16* WoT = (u16*)(ws + 33554432);
  u16* XBbf = (u16*)d_out;                       // d_out as scratch (dead before gemm<1>)
  u16* XAbf = (u16*)((char*)d_out + 33554432);

  conv_bf16<<<8192, 256, 0, stream>>>(hs, hsb);
  wt_conv<<<dim3(32, 32), 256, 0, stream>>>(Wq, WcatT, 2048, 2048);
  wt_conv<<<dim3(32, 32), 256, 0, stream>>>(Wk, WcatT + (size_t)2048 * 2048, 2048, 2048);
  wt_conv<<<dim3(32, 32), 256, 0, stream>>>(Wv, WcatT + (size_t)4096 * 2048, 2048, 2048);
  ilr_strip<<<1024, 256, 0, stream>>>(ilr_w, WcatT);

  gemm8p<0><<<dim3(25, 32), 512, 0, stream>>>(hsb, WcatT, 8192, 6272, 2048, XCbf, XBbf, XAbf,
                                              coeffb, ilr_b, nullptr);
  wt_conv<<<dim3(32, 32), 256, 0, stream>>>(Wo, WoT, 2048, 2048);
  ttt_scan<<<128, 64, 0, stream>>>(XCbf, XBbf, XAbf, coeffb, lnw, lnb, W1, b1, XCW);
  gemm8p<1><<<dim3(8, 32), 512, 0, stream>>>(XCW, WoT, 8192, 2048, 2048, nullptr, nullptr,
                                             nullptr, nullptr, nullptr, out);

  (void)in_sizes; (void)n_in; (void)out_size;
}

// Round 19
// 622.551 us; speedup vs baseline: 1.0127x; 1.0035x over previous
//
#include <hip/hip_runtime.h>
#include <hip/hip_bf16.h>

// ---------- types ----------
typedef __attribute__((ext_vector_type(8))) short bf16x8;   // 8 bf16 (K=32 MFMA)
typedef __attribute__((ext_vector_type(4))) short bf16x4;   // 4 bf16 (K=16 MFMA)
typedef __attribute__((ext_vector_type(4))) float f32x4;
typedef __attribute__((ext_vector_type(8))) unsigned short u16x8;
typedef unsigned short u16;

#define AS1(p) ((__attribute__((address_space(1))) void*)(p))
#define AS3(p) ((__attribute__((address_space(3))) void*)(p))
#define GLL16(g, l) __builtin_amdgcn_global_load_lds(AS1(g), AS3(l), 16, 0, 0)

__device__ __forceinline__ u16 f2bf(float x) {
  return __builtin_bit_cast(u16, __float2bfloat16(x));
}
__device__ __forceinline__ float bf2f(u16 u) {
  return __builtin_bit_cast(float, ((unsigned)u) << 16);
}
__device__ __forceinline__ f32x4 mfma16(bf16x8 a, bf16x8 b, f32x4 c) {
  return __builtin_amdgcn_mfma_f32_16x16x32_bf16(a, b, c, 0, 0, 0);
}
// K=16 MFMA (device-pass-only selection — R10 lesson)
__device__ __forceinline__ f32x4 mfma16k(bf16x4 a, bf16x4 b, f32x4 c) {
#if defined(__HIP_DEVICE_COMPILE__)
#if __has_builtin(__builtin_amdgcn_mfma_f32_16x16x16bf16_1k)
  return __builtin_amdgcn_mfma_f32_16x16x16bf16_1k(a, b, c, 0, 0, 0);
#else
  f32x4 d;
  asm volatile("v_mfma_f32_16x16x16_bf16 %0, %1, %2, %3"
               : "=v"(d)
               : "v"(a), "v"(b), "v"(c));
  return d;
#endif
#else
  (void)a; (void)b;
  return c;  // host pass: parse-only stub
#endif
}
// sum over each 16-lane row via DPP row_ror rotate-accumulate (VALU pipe)
#define DPPADD(x, ctrl)                                                            \
  ((x) + __builtin_bit_cast(float, __builtin_amdgcn_update_dpp(                    \
             0, __builtin_bit_cast(int, (x)), (ctrl), 0xf, 0xf, true)))
__device__ __forceinline__ float rsum16(float x) {
  x = DPPADD(x, 0x128);  // row_ror:8
  x = DPPADD(x, 0x124);  // row_ror:4
  x = DPPADD(x, 0x122);  // row_ror:2
  x = DPPADD(x, 0x121);  // row_ror:1
  return x;
}

// ---------- convert hs f32 -> bf16 (8 elems/thread) ----------
__global__ __launch_bounds__(256) void conv_bf16(const float* __restrict__ in,
                                                 u16* __restrict__ out) {
  size_t g = (size_t)blockIdx.x * 256 + threadIdx.x;
  const float4* p = reinterpret_cast<const float4*>(in) + g * 2;
  float4 a = p[0], b = p[1];
  u16x8 r;
  r[0] = f2bf(a.x); r[1] = f2bf(a.y); r[2] = f2bf(a.z); r[3] = f2bf(a.w);
  r[4] = f2bf(b.x); r[5] = f2bf(b.y); r[6] = f2bf(b.z); r[7] = f2bf(b.w);
  *reinterpret_cast<u16x8*>(out + g * 8) = r;
}

// ---------- transpose + convert: W[K][N] f32 -> Wt[N][K] bf16 ----------
__global__ __launch_bounds__(256) void wt_conv(const float* __restrict__ W,
                                               u16* __restrict__ Wt, int Kd, int N) {
  __shared__ float t[64][65];
  const int n0 = blockIdx.x * 64, k0 = blockIdx.y * 64;
  const int tx = threadIdx.x & 63, ty = threadIdx.x >> 6;
#pragma unroll
  for (int rr = 0; rr < 16; ++rr) {
    int r = rr * 4 + ty;
    t[r][tx] = W[(size_t)(k0 + r) * N + n0 + tx];
  }
  __syncthreads();
#pragma unroll
  for (int rr = 0; rr < 16; ++rr) {
    int r = rr * 4 + ty;
    Wt[(size_t)(n0 + r) * Kd + k0 + tx] = f2bf(t[tx][r]);
  }
}

// ---------- ilr_w strip into WcatT rows [6144,6272) ----------
__global__ __launch_bounds__(256) void ilr_strip(const float* __restrict__ ilr_w,
                                                 u16* __restrict__ WcatT) {
  int g = blockIdx.x * 256 + threadIdx.x;  // 128*2048
  int p = g >> 11, k = g & 2047;
  float v = (p < 32) ? ilr_w[k * 32 + p] : 0.f;
  WcatT[(size_t)(6144 + p) * 2048 + k] = f2bf(v);
}

// ---------- 256x256x64 8-phase GEMM (T3+T4+T2+T5 + T1 XCD swizzle) ----------
template <int MODE>
__global__ __launch_bounds__(512) void gemm8p(const u16* __restrict__ A,
                                              const u16* __restrict__ Bt, int M, int N, int Kd,
                                              u16* __restrict__ O0, u16* __restrict__ O1,
                                              u16* __restrict__ O2,
                                              float* __restrict__ coeffOut,
                                              const float* __restrict__ ilrb,
                                              float* __restrict__ Cout) {
  __shared__ __align__(16) u16 Asm[2][2][8192];
  __shared__ __align__(16) u16 Bsm[2][2][8192];
  const int tid = threadIdx.x;
  const int lane = tid & 63, wid = tid >> 6;
  const int wr = wid >> 2, wc = wid & 3;
  const int l15 = lane & 15, l4 = lane >> 4;
  const int wc1 = wc & 1, wch = wc >> 1;
  const int swzm = (l15 & 3) ^ (((l15 >> 2) & 1) << 2);
  // T1: XCD-aware bijective block swizzle (grids are %8==0: 800 and 256 blocks)
  const int nwg = gridDim.x * gridDim.y;
  int bid = blockIdx.y * gridDim.x + blockIdx.x;
  bid = (bid & 7) * (nwg >> 3) + (bid >> 3);
  const int bx = bid % gridDim.x, by = bid / gridDim.x;
  const int mT = by << 8, nT = bx << 8;
  const int nKt = Kd >> 6;

#define STG_A(kt_, h_)                                                              \
  do {                                                                              \
    if ((kt_) < nKt) {                                                              \
      _Pragma("unroll") for (int i_ = 0; i_ < 2; ++i_) {                            \
        const int s_ = tid + 512 * i_;                                              \
        const int r_ = s_ >> 3;                                                     \
        const int sc_ = (s_ & 7) ^ (r_ & 3) ^ (((r_ >> 2) & 1) << 2);               \
        GLL16(A + (size_t)(mT + (h_) * 128 + r_) * Kd + (kt_) * 64 + sc_ * 8,       \
              &Asm[(kt_) & 1][h_][0] + s_ * 8);                                     \
      }                                                                             \
    }                                                                               \
  } while (0)
#define STG_B(kt_, h_)                                                              \
  do {                                                                              \
    if ((kt_) < nKt) {                                                              \
      _Pragma("unroll") for (int i_ = 0; i_ < 2; ++i_) {                            \
        const int s_ = tid + 512 * i_;                                              \
        const int r_ = s_ >> 3;                                                     \
        const int sc_ = (s_ & 7) ^ (r_ & 3) ^ (((r_ >> 2) & 1) << 2);               \
        const int rg_ = nT + (h_) * 128 + r_;                                       \
        if (rg_ < N)                                                                \
          GLL16(Bt + (size_t)rg_ * Kd + (kt_) * 64 + sc_ * 8,                       \
                &Bsm[(kt_) & 1][h_][0] + s_ * 8);                                   \
      }                                                                             \
    }                                                                               \
  } while (0)
#define RD_A(buf_, mi_, ks_)                                                        \
  (*(const bf16x8*)((const char*)&Asm[buf_][wr][0] + 128 * ((mi_) * 16 + l15) +     \
                    16 * ((l4 + 4 * (ks_)) ^ swzm)))
#define RD_B(buf_, ni_, ks_)                                                        \
  (*(const bf16x8*)((const char*)&Bsm[buf_][wch][0] +                               \
                    128 * (wc1 * 64 + (ni_) * 16 + l15) +                           \
                    16 * ((l4 + 4 * (ks_)) ^ swzm)))
#define BARRIER __builtin_amdgcn_s_barrier()
#define LGKM0                                                                       \
  do {                                                                              \
    asm volatile("s_waitcnt lgkmcnt(0)" ::: "memory");                              \
    __builtin_amdgcn_sched_barrier(0);                                              \
  } while (0)
#define VM4 asm volatile("s_waitcnt vmcnt(4)" ::: "memory")
#define PRIO1 __builtin_amdgcn_s_setprio(1)
#define PRIO0 __builtin_amdgcn_s_setprio(0)
#define QUAD(mh_, nh_)                                                              \
  _Pragma("unroll") for (int m4_ = 0; m4_ < 4; ++m4_)                               \
  _Pragma("unroll") for (int n2_ = 0; n2_ < 2; ++n2_)                               \
  _Pragma("unroll") for (int ks_ = 0; ks_ < 2; ++ks_)                               \
      acc[(mh_) * 4 + m4_][(nh_) * 2 + n2_] =                                       \
          mfma16(Af[(mh_) * 4 + m4_][ks_], Bf[(nh_) * 2 + n2_][ks_],                \
                 acc[(mh_) * 4 + m4_][(nh_) * 2 + n2_])

  f32x4 acc[8][4];
#pragma unroll
  for (int m = 0; m < 8; ++m)
#pragma unroll
    for (int n = 0; n < 4; ++n) acc[m][n] = (f32x4){0.f, 0.f, 0.f, 0.f};
  bf16x8 Af[8][2], Bf[4][2];

  STG_A(0, 0); STG_A(0, 1); STG_B(0, 0); STG_B(0, 1); STG_A(1, 0); STG_A(1, 1);
  VM4;
  BARRIER;

#pragma unroll 1
  for (int it = 0; it < (nKt >> 1); ++it) {
    const int T = 2 * it;
#pragma unroll
    for (int mi = 0; mi < 4; ++mi)
#pragma unroll
      for (int ks = 0; ks < 2; ++ks) Af[mi][ks] = RD_A(0, mi, ks);
#pragma unroll
    for (int ni = 0; ni < 2; ++ni)
#pragma unroll
      for (int ks = 0; ks < 2; ++ks) Bf[ni][ks] = RD_B(0, ni, ks);
    STG_B(T + 1, 0);
    BARRIER; LGKM0; PRIO1; QUAD(0, 0); PRIO0;
    BARRIER;
#pragma unroll
    for (int mi = 4; mi < 8; ++mi)
#pragma unroll
      for (int ks = 0; ks < 2; ++ks) Af[mi][ks] = RD_A(0, mi, ks);
    STG_B(T + 1, 1);
    BARRIER; LGKM0; PRIO1; QUAD(1, 0); PRIO0;
    BARRIER;
#pragma unroll
    for (int ni = 2; ni < 4; ++ni)
#pragma unroll
      for (int ks = 0; ks < 2; ++ks) Bf[ni][ks] = RD_B(0, ni, ks);
    STG_A(T + 2, 0);
    BARRIER; LGKM0; PRIO1; QUAD(0, 1); PRIO0;
    BARRIER;
    STG_A(T + 2, 1);
    BARRIER; LGKM0; PRIO1; QUAD(1, 1); PRIO0;
    VM4;
    BARRIER;
#pragma unroll
    for (int mi = 0; mi < 4; ++mi)
#pragma unroll
      for (int ks = 0; ks < 2; ++ks) Af[mi][ks] = RD_A(1, mi, ks);
#pragma unroll
    for (int ni = 0; ni < 2; ++ni)
#pragma unroll
      for (int ks = 0; ks < 2; ++ks) Bf[ni][ks] = RD_B(1, ni, ks);
    STG_B(T + 2, 0);
    BARRIER; LGKM0; PRIO1; QUAD(0, 0); PRIO0;
    BARRIER;
#pragma unroll
    for (int mi = 4; mi < 8; ++mi)
#pragma unroll
      for (int ks = 0; ks < 2; ++ks) Af[mi][ks] = RD_A(1, mi, ks);
    STG_B(T + 2, 1);
    BARRIER; LGKM0; PRIO1; QUAD(1, 0); PRIO0;
    BARRIER;
#pragma unroll
    for (int ni = 2; ni < 4; ++ni)
#pragma unroll
      for (int ks = 0; ks < 2; ++ks) Bf[ni][ks] = RD_B(1, ni, ks);
    STG_A(T + 3, 0);
    BARRIER; LGKM0; PRIO1; QUAD(0, 1); PRIO0;
    BARRIER;
    STG_A(T + 3, 1);
    BARRIER; LGKM0; PRIO1; QUAD(1, 1); PRIO0;
    VM4;
    BARRIER;
  }

#pragma unroll
  for (int mi = 0; mi < 8; ++mi) {
#pragma unroll
    for (int ni = 0; ni < 4; ++ni) {
      const int col = nT + wc * 64 + ni * 16 + l15;
#pragma unroll
      for (int e = 0; e < 4; ++e) {
        const int row = mT + wr * 128 + mi * 16 + l4 * 4 + e;
        float v = acc[mi][ni][e];
        if constexpr (MODE == 1) {
          Cout[(size_t)row * N + col] = v;
        } else {
          const int bb = row >> 11, lt = row & 2047;
          if (col < 6144) {
            const int mat = col >> 11;
            u16* base = (mat == 0) ? O0 : ((mat == 1) ? O1 : O2);
            const int hh = (col >> 6) & 31, dd = col & 63;
            base[(((size_t)(bb * 32 + hh)) * 2048 + lt) * 64 + dd] = f2bf(v);
          } else {
            const int h3 = col - 6144;
            if (h3 < 32) {
              const float x = v + ilrb[h3];
              const float sig = 1.f / (1.f + expf(-x));
              const int tok = lt & 15;
              coeffOut[((size_t)(bb * 32 + h3)) * 2048 + lt] =
                  sig * (1.f / (64.f * (float)(tok + 1)));
            }
          }
        }
      }
    }
  }
  (void)M;
#undef STG_A
#undef STG_B
#undef RD_A
#undef RD_B
#undef QUAD
}

// ---------- 1-wave-per-(b,h) zero-LDS TTT scan (unroll-2 pipelined, R16-proven) ----------
// 128 blocks x 64 thr. unroll 2 is the measured optimum (R16: 245us; R17 unroll-4
// regressed to 287us via register pressure, VGPR 168->220).
__global__ __launch_bounds__(64) void ttt_scan(
    const u16* __restrict__ XC, const u16* __restrict__ XB, const u16* __restrict__ XA,
    const float* __restrict__ coeff, const float* __restrict__ lnw_g,
    const float* __restrict__ lnb_g, const float* __restrict__ W1g,
    const float* __restrict__ b1g, u16* __restrict__ XCW) {
  const int bh = blockIdx.x;
  const int b = bh >> 5, h = bh & 31;
  const int lane = threadIdx.x & 63;
  const int l15 = lane & 15, l4 = lane >> 4;

  const u16* xbb = XB + (size_t)bh * 131072;
  const u16* xcb = XC + (size_t)bh * 131072;
  const u16* xab = XA + (size_t)bh * 131072;
  const float* cob = coeff + (size_t)bh * 2048;

  float lnw4[4], lnb4[4], b1m[4];
#pragma unroll
  for (int cb = 0; cb < 4; ++cb) {
    lnw4[cb] = lnw_g[h * 64 + cb * 16 + l15];
    lnb4[cb] = lnb_g[h * 64 + cb * 16 + l15];
    b1m[cb] = b1g[h * 64 + cb * 16 + l15];
  }
  f32x4 mW[4][4];
#pragma unroll
  for (int kb = 0; kb < 4; ++kb)
#pragma unroll
    for (int cb = 0; cb < 4; ++cb)
#pragma unroll
      for (int e = 0; e < 4; ++e)
        mW[kb][cb][e] = W1g[(size_t)h * 4096 + (kb * 16 + l4 * 4 + e) * 64 + cb * 16 + l15];

  // identity B-frag: I[k=l4*4+e][n=l15] -> mfma16k(xA, I) = x in C-layout (transpose)
  bf16x4 identf;
#pragma unroll
  for (int e = 0; e < 4; ++e)
    identf[e] = (short)((l4 * 4 + e == l15) ? 0x3F80 : 0);
  const f32x4 zero4 = {0.f, 0.f, 0.f, 0.f};

  uint2 nxbA[4], nxcA[4], nxaA[4];
  float nco[4], nco15, ncoL;
  const int foA = l15 * 128 + l4 * 8;
#define PF(cc)                                                                       \
  do {                                                                               \
    const char* pb = (const char*)(xbb + (cc) * 1024);                               \
    const char* pc = (const char*)(xcb + (cc) * 1024);                               \
    const char* pa = (const char*)(xab + (cc) * 1024);                               \
    _Pragma("unroll") for (int kb = 0; kb < 4; ++kb) {                               \
      nxbA[kb] = *(const uint2*)(pb + foA + kb * 32);                                \
      nxcA[kb] = *(const uint2*)(pc + foA + kb * 32);                                \
      nxaA[kb] = *(const uint2*)(pa + foA + kb * 32);                                \
    }                                                                                \
    _Pragma("unroll") for (int e = 0; e < 4; ++e) nco[e] = cob[(cc) * 16 + l4 * 4 + e]; \
    nco15 = cob[(cc) * 16 + 15];                                                     \
    ncoL = cob[(cc) * 16 + l15];                                                     \
  } while (0)

  PF(0);

#pragma unroll 2
  for (int c = 0; c < 128; ++c) {
    bf16x4 xbA[4], xcA[4], xaA[4];
#pragma unroll
    for (int kb = 0; kb < 4; ++kb) {
      xbA[kb] = __builtin_bit_cast(bf16x4, nxbA[kb]);
      xcA[kb] = __builtin_bit_cast(bf16x4, nxcA[kb]);
      xaA[kb] = __builtin_bit_cast(bf16x4, nxaA[kb]);
    }
    float co_own[4];
#pragma unroll
    for (int e = 0; e < 4; ++e) co_own[e] = nco[e];
    const float co15 = nco15, coL = ncoL;

    // prefetch next chunk (only VMEM in steady state)
    PF((c < 127) ? (c + 1) : 127);

    // ---- C-layout operands via identity transpose (no loads) ----
    f32x4 saC[4], sbC[4], scC[4];
#pragma unroll
    for (int kb = 0; kb < 4; ++kb) {
      saC[kb] = mfma16k(xaA[kb], identf, zero4);
      sbC[kb] = mfma16k(xbA[kb], identf, zero4);
      scC[kb] = mfma16k(xcA[kb], identf, zero4);
    }

    // ---- P^T = xb @ xc^T ; pack A-frag ----
    f32x4 pT = zero4;
#pragma unroll
    for (int kb = 0; kb < 4; ++kb) pT = mfma16k(xbA[kb], xcA[kb], pT);
    bf16x4 pTf;
#pragma unroll
    for (int e = 0; e < 4; ++e) {
      const int r = l4 * 4 + e;
      pTf[e] = (short)f2bf((r <= l15) ? pT[e] * (-coL) : 0.f);
    }

    // ---- W1 master -> bf16 B-frags ----
    bf16x4 w1b[4][4];
#pragma unroll
    for (int kb = 0; kb < 4; ++kb)
#pragma unroll
      for (int cb = 0; cb < 4; ++cb)
#pragma unroll
        for (int e = 0; e < 4; ++e) w1b[kb][cb][e] = (short)f2bf(mW[kb][cb][e]);

    // ---- Z1 = xb@W1 + b1 ; o2 = xc@W1 ----
    f32x4 z[4], o2[4];
#pragma unroll
    for (int cb = 0; cb < 4; ++cb) {
      f32x4 a = {b1m[cb], b1m[cb], b1m[cb], b1m[cb]};
#pragma unroll
      for (int kb = 0; kb < 4; ++kb) a = mfma16k(xbA[kb], w1b[kb][cb], a);
      z[cb] = a;
      f32x4 a2 = zero4;
#pragma unroll
      for (int kb = 0; kb < 4; ++kb) a2 = mfma16k(xcA[kb], w1b[kb][cb], a2);
      o2[cb] = a2;
    }

    // ---- LN backward (DPP row-reductions; operands register-resident) ----
    float gr[4][4];
#pragma unroll
    for (int e = 0; e < 4; ++e) {
      float zz[4];
#pragma unroll
      for (int cb = 0; cb < 4; ++cb) zz[cb] = z[cb][e];
      float s1 = zz[0] + zz[1] + zz[2] + zz[3];
      float s2 = zz[0] * zz[0] + zz[1] * zz[1] + zz[2] * zz[2] + zz[3] * zz[3];
      s1 = rsum16(s1);
      s2 = rsum16(s2);
      const float mu = s1 * 0.015625f;
      const float var = fmaxf(s2 * 0.015625f - mu * mu, 0.f);
      const float rstd = rsqrtf(var + 1e-6f);
      float xh[4], gl[4];
#pragma unroll
      for (int cb = 0; cb < 4; ++cb) {
        xh[cb] = (zz[cb] - mu) * rstd;
        const float tgt = saC[cb][e] - sbC[cb][e];
        gl[cb] = (fmaf(lnw4[cb], xh[cb], lnb4[cb]) - tgt) * lnw4[cb];
      }
      float gs = gl[0] + gl[1] + gl[2] + gl[3];
      float gx = gl[0] * xh[0] + gl[1] * xh[1] + gl[2] * xh[2] + gl[3] * xh[3];
      gs = rsum16(gs);
      gx = rsum16(gx);
#pragma unroll
      for (int cb = 0; cb < 4; ++cb)
        gr[cb][e] = (64.f * gl[cb] - gs - xh[cb] * gx) * (rstd * 0.015625f);
    }

    // ---- column totals / prefix ----
    float gtot[4], lower[4];
#pragma unroll
    for (int cb = 0; cb < 4; ++cb) {
      const float T = gr[cb][0] + gr[cb][1] + gr[cb][2] + gr[cb][3];
      const float t1 = __shfl_xor(T, 16, 64);
      const float t2 = __shfl_xor(T, 32, 64);
      const float t3 = __shfl_xor(t1, 32, 64);
      gtot[cb] = T + t1 + t2 + t3;
      lower[cb] = ((l4 & 1) ? t1 : 0.f) + ((l4 & 2) ? (t2 + t3) : 0.f);
    }

    // ---- grad C-layout == B-frag: pack ----
    bf16x4 grB[4];
#pragma unroll
    for (int cb = 0; cb < 4; ++cb)
#pragma unroll
      for (int e = 0; e < 4; ++e) grB[cb][e] = (short)f2bf(gr[cb][e]);

    // ---- Z1_bar += (-co*P)@grad ----
#pragma unroll
    for (int cb = 0; cb < 4; ++cb) o2[cb] = mfma16k(pTf, grB[cb], o2[cb]);

    // ---- W1 update: A = -co15*xb^T (C-layout from transpose), B = grB ----
    bf16x4 xbU[4];
#pragma unroll
    for (int kb = 0; kb < 4; ++kb)
#pragma unroll
      for (int e = 0; e < 4; ++e)
        xbU[kb][e] = (short)f2bf(sbC[kb][e] * (-co15));
#pragma unroll
    for (int kb = 0; kb < 4; ++kb)
#pragma unroll
      for (int cb = 0; cb < 4; ++cb) mW[kb][cb] = mfma16k(xbU[kb], grB[cb], mW[kb][cb]);

    // ---- b1_bar, output LN, store ----
    float ov[4][4];
#pragma unroll
    for (int cb = 0; cb < 4; ++cb) {
      float pfx = lower[cb];
#pragma unroll
      for (int e = 0; e < 4; ++e) {
        pfx += gr[cb][e];
        ov[cb][e] = o2[cb][e] + fmaf(-co_own[e], pfx, b1m[cb]);
      }
    }
#pragma unroll
    for (int e = 0; e < 4; ++e) {
      float s1 = ov[0][e] + ov[1][e] + ov[2][e] + ov[3][e];
      float s2 = ov[0][e] * ov[0][e] + ov[1][e] * ov[1][e] + ov[2][e] * ov[2][e] +
                 ov[3][e] * ov[3][e];
      s1 = rsum16(s1);
      s2 = rsum16(s2);
      const float mu = s1 * 0.015625f;
      const float var = fmaxf(s2 * 0.015625f - mu * mu, 0.f);
      const float rstd = rsqrtf(var + 1e-6f);
      const size_t rowg = (size_t)(b * 2048 + c * 16 + l4 * 4 + e) * 2048 + h * 64;
#pragma unroll
      for (int cb = 0; cb < 4; ++cb) {
        const float y = scC[cb][e] + fmaf(lnw4[cb], (ov[cb][e] - mu) * rstd, lnb4[cb]);
        XCW[rowg + cb * 16 + l15] = f2bf(y);
      }
    }

#pragma unroll
    for (int cb = 0; cb < 4; ++cb) b1m[cb] = fmaf(-co15, gtot[cb], b1m[cb]);
  }
#undef PF
}

// ---------- launcher ----------
extern "C" void kernel_launch(void* const* d_in, const int* in_sizes, int n_in, void* d_out,
                              int out_size, void* d_ws, size_t ws_size, hipStream_t stream) {
  const float* hs = (const float*)d_in[0];
  const float* Wq = (const float*)d_in[1];
  const float* Wk = (const float*)d_in[2];
  const float* Wv = (const float*)d_in[3];
  const float* Wo = (const float*)d_in[4];
  const float* ilr_w = (const float*)d_in[5];
  const float* ilr_b = (const float*)d_in[6];
  const float* lnw = (const float*)d_in[7];
  const float* lnb = (const float*)d_in[8];
  const float* W1 = (const float*)d_in[9];
  const float* b1 = (const float*)d_in[10];
  float* out = (float*)d_out;

  if (ws_size < 93847552u) return;  // diagnosable clean-fail instead of device fault
  char* ws = (char*)d_ws;
  u16* hsb = (u16*)(ws + 0);                 // 33.5 MB; reused as XCW after gemm<0>
  u16* WcatT = (u16*)(ws + 33554432);        // 25.7 MB; reused as WoT after gemm<0>
  u16* XCbf = (u16*)(ws + 59244544);         // 33.5 MB
  float* coeffb = (float*)(ws + 92798976);   // 1 MB
  u16* XCW = hsb;
  u16* WoT = (u16*)(ws + 33554432);
  u16* XBbf = (u16*)d_out;                       // d_out as scratch (dead before gemm<1>)
  u16* XAbf = (u16*)((char*)d_out + 33554432);

  conv_bf16<<<8192, 256, 0, stream>>>(hs, hsb);
  wt_conv<<<dim3(32, 32), 256, 0, stream>>>(Wq, WcatT, 2048, 2048);
  wt_conv<<<dim3(32, 32), 256, 0, stream>>>(Wk, WcatT + (size_t)2048 * 2048, 2048, 2048);
  wt_conv<<<dim3(32, 32), 256, 0, stream>>>(Wv, WcatT + (size_t)4096 * 2048, 2048, 2048);
  ilr_strip<<<1024, 256, 0, stream>>>(ilr_w, WcatT);

  gemm8p<0><<<dim3(25, 32), 512, 0, stream>>>(hsb, WcatT, 8192, 6272, 2048, XCbf, XBbf, XAbf,
                                              coeffb, ilr_b, nullptr);
  wt_conv<<<dim3(32, 32), 256, 0, stream>>>(Wo, WoT, 2048, 2048);
  ttt_scan<<<128, 64, 0, stream>>>(XCbf, XBbf, XAbf, coeffb, lnw, lnb, W1, b1, XCW);
  gemm8p<1><<<dim3(8, 32), 512, 0, stream>>>(XCW, WoT, 8192, 2048, 2048, nullptr, nullptr,
                                             nullptr, nullptr, nullptr, out);

  (void)in_sizes; (void)n_in; (void)out_size;
}